// Round 12
// baseline (338.839 us; speedup 1.0000x reference)
//
#include <hip/hip_runtime.h>
#include <hip/hip_bf16.h>
#include <stdint.h>

#define N_NODES 50000
#define N_EDGES 800000
#define D_IN    128
#define H_DIM   256
#define BN_EPS  1e-5f
#define LN_EPS  1e-5f
#define NBLK2 782      // ceil(50000/64) node-groups for agg (64 nodes/block)
#define SLICE_ELEMS ((size_t)N_NODES * 32)
#define EDGE_CHUNK 4096   // edges cached in LDS per agg block
#define BN0_BLOCKS 1024
#define TR_BLOCKS 256     // 65536/256
#define NBKT 196          // coarse buckets: dst >> 8
#define CHUNK 2048        // edges per radix block
#define RCHUNKS 391       // ceil(800000/2048)

typedef float v4f __attribute__((ext_vector_type(4)));
typedef float v2f __attribute__((ext_vector_type(2)));
typedef short v8s __attribute__((ext_vector_type(8)));
typedef unsigned v4u __attribute__((ext_vector_type(4)));

__device__ __forceinline__ float bflo(unsigned u){ return __uint_as_float(u << 16); }
__device__ __forceinline__ float bfhi(unsigned u){ return __uint_as_float(u & 0xffff0000u); }
__device__ __forceinline__ unsigned short f2bf(float f){
  unsigned u = __float_as_uint(f);
  u += 0x7fffu + ((u >> 16) & 1u);
  return (unsigned short)(u >> 16);
}
__device__ __forceinline__ unsigned pack2(float a, float b){
  return (unsigned)f2bf(a) | ((unsigned)f2bf(b) << 16);
}

__device__ __forceinline__ int block_excl_scan(int v){
  int t = threadIdx.x;
  int lane = t & 63, w = t >> 6;
  int inc = v;
  #pragma unroll
  for (int m = 1; m < 64; m <<= 1){
    int o = __shfl_up(inc, m, 64);
    if (lane >= m) inc += o;
  }
  __shared__ int wsum[4];
  if (lane == 63) wsum[w] = inc;
  __syncthreads();
  int base = 0;
  #pragma unroll
  for (int j = 0; j < 4; ++j) if (j < w) base += wsum[j];
  return base + inc - v;  // exclusive
}

// ---------------- fused: BN0 stats (blocks 0..1023, 8 rotation buffers) || coarse bucket histogram ----------------
__global__ __launch_bounds__(256) void bn0r1_k(const int* ei, const float* x,
                                               const float* fs, const float* fb,
                                               float* S, float* Q, int* ghist){
  int b = blockIdx.x, t = threadIdx.x;
  if (b >= BN0_BLOCKS){
    __shared__ int lh[NBKT];
    int b2 = b - BN0_BLOCKS;
    for (int i = t; i < NBKT; i += 256) lh[i] = 0;
    __syncthreads();
    int e0 = b2 * CHUNK;
    int n = min(CHUNK, N_EDGES - e0);
    for (int i = t; i < n; i += 256)
      atomicAdd(&lh[ei[N_EDGES + e0 + i] >> 8], 1);
    __syncthreads();
    if (t < NBKT && lh[t] > 0) atomicAdd(&ghist[t], lh[t]);
    return;
  }
  int cl = t & 31, rg = t >> 5;
  int c = cl * 4;
  float4 fs4 = *(const float4*)(fs + c);
  float4 fb4 = *(const float4*)(fb + c);
  float s0=0,s1=0,s2=0,s3=0,q0=0,q1=0,q2=0,q3=0;
  for (int row = b * 8 + rg; row < N_NODES; row += BN0_BLOCKS * 8){
    float4 xv = *(const float4*)(x + (size_t)row * D_IN + c);
    float v0 = xv.x * fs4.x + fb4.x;
    float v1 = xv.y * fs4.y + fb4.y;
    float v2 = xv.z * fs4.z + fb4.z;
    float v3 = xv.w * fs4.w + fb4.w;
    s0 += v0; s1 += v1; s2 += v2; s3 += v3;
    q0 += v0*v0; q1 += v1*v1; q2 += v2*v2; q3 += v3*v3;
  }
  __shared__ float red[256][8];
  red[t][0]=s0; red[t][1]=s1; red[t][2]=s2; red[t][3]=s3;
  red[t][4]=q0; red[t][5]=q1; red[t][6]=q2; red[t][7]=q3;
  __syncthreads();
  float* Sr = S + (b & 7) * D_IN;
  float* Qr = Q + (b & 7) * D_IN;
  if (t < 32){
    float a[8];
    #pragma unroll
    for (int i = 0; i < 8; ++i) a[i] = red[t][i];
    for (int j = 1; j < 8; ++j)
      #pragma unroll
      for (int i = 0; i < 8; ++i) a[i] += red[t + 32*j][i];
    #pragma unroll
    for (int i = 0; i < 4; ++i){ atomicAdd(&Sr[t*4+i], a[i]); atomicAdd(&Qr[t*4+i], a[4+i]); }
  }
}

// ---------------- coarse scatter: edges -> ebuf bucketed by dst>>8 (LDS atomics; in-block ghist scan) ----------------
__global__ __launch_bounds__(256) void r3_k(const int* ei, const int* ghist, int* gcursor, unsigned* ebuf){
  __shared__ unsigned short dstS[CHUNK];
  __shared__ int lh[NBKT], cb[NBKT], sbb[NBKT];
  int t = threadIdx.x;
  int v = (t < NBKT) ? ghist[t] : 0;
  int epre = block_excl_scan(v);
  if (t < NBKT){ sbb[t] = epre; lh[t] = 0; }
  __syncthreads();
  int e0 = blockIdx.x * CHUNK;
  int n = min(CHUNK, N_EDGES - e0);
  for (int i = t; i < n; i += 256){
    int d = ei[N_EDGES + e0 + i];
    dstS[i] = (unsigned short)d;
    atomicAdd(&lh[d >> 8], 1);
  }
  __syncthreads();
  if (t < NBKT && lh[t] > 0) cb[t] = sbb[t] + atomicAdd(&gcursor[t], lh[t]);
  __syncthreads();
  if (t < NBKT) lh[t] = 0;
  __syncthreads();
  for (int i = t; i < n; i += 256){
    int d = dstS[i];
    int bkt = d >> 8;
    int r = atomicAdd(&lh[bkt], 1);
    unsigned src = (unsigned)ei[e0 + i];
    ebuf[cb[bkt] + r] = ((unsigned)(d & 255) << 16) | src;
  }
}

// ---------------- fused: per-bucket degree sort + edge scatter (blocks 0..195) || weight transpose ----------------
__global__ __launch_bounds__(256) void sortprep_k(const unsigned* ebuf, const int* ghist,
                                                  int* perm, int* offs, float* dinv,
                                                  unsigned short* edges,
                                                  const float* W1, const float* W2,
                                                  unsigned short* W1t, unsigned short* W2t){
  int b = blockIdx.x, t = threadIdx.x;
  if (b < NBKT){
    __shared__ int h[256], dh[128], ep_s[128], W_s[128], lc[128], curs[256], sbb[NBKT + 1];
    int gv = (t < NBKT) ? ghist[t] : 0;
    int gpre = block_excl_scan(gv);
    if (t < NBKT) sbb[t] = gpre;
    if (t == NBKT - 1) sbb[NBKT] = gpre + gv;
    h[t] = 0;
    if (t < 128){ dh[t] = 0; lc[t] = 0; }
    __syncthreads();
    int lo = sbb[b], hi = sbb[b + 1];
    for (int i = lo + t; i < hi; i += 256)
      atomicAdd(&h[(ebuf[i] >> 16) & 255], 1);
    __syncthreads();
    int node = b * 256 + t;
    bool valid = node < N_NODES;
    int deg = valid ? h[t] : 0;
    if (valid) atomicAdd(&dh[min(deg, 127)], 1);
    __syncthreads();
    int cv = (t < 128) ? dh[t] : 0;
    int e1 = block_excl_scan(cv);
    __syncthreads();
    int e2 = block_excl_scan((t < 128) ? cv * t : 0);
    __syncthreads();
    if (t < 128){ ep_s[t] = e1; W_s[t] = e2; }
    __syncthreads();
    if (valid){
      int bin = min(deg, 127);
      int r = atomicAdd(&lc[bin], 1);
      int pl = ep_s[bin] + r;              // local (within-bucket) rank
      int pos = b * 256 + pl;              // global position: buckets are contiguous
      int off = lo + W_s[bin] + (pl - ep_s[bin]) * deg;  // all nodes in bin have degree == bin
      perm[pos] = node;
      offs[pos] = off;
      dinv[node] = rsqrtf((float)deg + 1.0f);
      curs[t] = off;                        // scatter cursor, indexed by node low byte (== t)
    }
    __syncthreads();
    for (int i = lo + t; i < hi; i += 256){
      unsigned u = ebuf[i];
      int l8 = (u >> 16) & 255;
      int pos = atomicAdd(&curs[l8], 1);
      edges[pos] = (unsigned short)(u & 0xffffu);
    }
    if (b == 0 && t == 0) offs[N_NODES] = N_EDGES;
    return;
  }
  int i = (b - NBKT) * 256 + t;
  if (i < D_IN * H_DIM){
    int r = i / H_DIM, c = i % H_DIM;
    W1t[c * D_IN + r] = f2bf(W1[i]);
  }
  if (i < H_DIM * H_DIM){
    int r = i / H_DIM, c = i % H_DIM;
    W2t[c * H_DIM + r] = f2bf(W2[i]);
  }
}

// ---------------- layer-1 GEMM: 128x256 tile, 512 threads (8 waves, 2Mx4N), BN0 fused into A-staging ----------------
__global__ __launch_bounds__(512) void gemm1_k(const float* x, const float* S, const float* Q,
                                               const float* fs, const float* fb,
                                               const float* gg, const float* bb,
                                               const unsigned short* Bt, const float* dinv,
                                               unsigned short* C, int M){
  __shared__ __align__(16) short smem[16896]; // staging: As[128][40]=5120 + Bs[256][40]=10240 shorts; epilogue Cs[64][264]=16896 aliases
  __shared__ float ac[128], cc[128], dvs[128];
  short* As = smem;
  short* Bs = smem + 128 * 40;
  int t = threadIdx.x;
  int m0 = blockIdx.x * 128;
  int lane = t & 63, w = t >> 6;
  int wr = w >> 2, wc = w & 3;           // wave row-half (2) x col-quarter (4)
  int fr = lane & 15, quad = lane >> 4;
  if (t < 128){
    dvs[t] = (m0 + t < M) ? dinv[m0 + t] : 0.0f;
    float s8 = 0.f, q8 = 0.f;
    #pragma unroll
    for (int rep = 0; rep < 8; ++rep){ s8 += S[rep * D_IN + t]; q8 += Q[rep * D_IN + t]; }
    const float invN = 1.0f / N_NODES;
    float mu = s8 * invN;
    float rs = rsqrtf(q8 * invN - mu * mu + BN_EPS);
    float a = gg[t] * rs * fs[t];
    ac[t] = a;
    cc[t] = gg[t] * rs * (fb[t] - mu) + bb[t];
  }
  __syncthreads();
  v4f acc[4][4] = {};
  int ar = t >> 2, aq = t & 3;           // A staging: 128 rows x 4 col-quarters
  int br = t >> 1, bh = t & 1;           // B staging: 256 rows x 2 halves
  for (int k0 = 0; k0 < D_IN; k0 += 32){
    __syncthreads();
    {
      int arow = m0 + ar;
      int c = k0 + aq * 8;
      float4 xv0 = {0,0,0,0}, xv1 = {0,0,0,0};
      if (arow < M){
        xv0 = *(const float4*)(x + (size_t)arow * D_IN + c);
        xv1 = *(const float4*)(x + (size_t)arow * D_IN + c + 4);
      }
      float4 a0 = *(const float4*)(&ac[c]);
      float4 a1 = *(const float4*)(&ac[c + 4]);
      float4 c0 = *(const float4*)(&cc[c]);
      float4 c1 = *(const float4*)(&cc[c + 4]);
      uint4 o;
      o.x = pack2(a0.x * xv0.x + c0.x, a0.y * xv0.y + c0.y);
      o.y = pack2(a0.z * xv0.z + c0.z, a0.w * xv0.w + c0.w);
      o.z = pack2(a1.x * xv1.x + c1.x, a1.y * xv1.y + c1.y);
      o.w = pack2(a1.z * xv1.z + c1.z, a1.w * xv1.w + c1.w);
      *(uint4*)(&As[ar * 40 + aq * 8]) = o;
    }
    {
      const unsigned short* bp = Bt + (size_t)br * D_IN + k0 + bh * 16;
      uint4 b0 = *(const uint4*)(bp);
      uint4 b1 = *(const uint4*)(bp + 8);
      *(uint4*)(&Bs[br * 40 + bh * 16]) = b0;
      *(uint4*)(&Bs[br * 40 + bh * 16 + 8]) = b1;
    }
    __syncthreads();
    v8s af[4], bf[4];
    #pragma unroll
    for (int mi = 0; mi < 4; ++mi)
      af[mi] = *(const v8s*)(&As[(wr * 64 + mi * 16 + fr) * 40 + quad * 8]);
    #pragma unroll
    for (int ni = 0; ni < 4; ++ni)
      bf[ni] = *(const v8s*)(&Bs[(wc * 64 + ni * 16 + fr) * 40 + quad * 8]);
    #pragma unroll
    for (int mi = 0; mi < 4; ++mi)
      #pragma unroll
      for (int ni = 0; ni < 4; ++ni)
        acc[mi][ni] = __builtin_amdgcn_mfma_f32_16x16x32_bf16(af[mi], bf[ni], acc[mi][ni], 0, 0, 0);
  }
  // epilogue in two 64-row halves; Cs aliases staging LDS
  short* Cs = smem; // [64][264]
  #pragma unroll
  for (int h = 0; h < 2; ++h){
    __syncthreads();
    if (wr == h){
      #pragma unroll
      for (int mi = 0; mi < 4; ++mi)
        #pragma unroll
        for (int ni = 0; ni < 4; ++ni)
          #pragma unroll
          for (int r = 0; r < 4; ++r){
            int row = mi * 16 + quad * 4 + r;
            int col = wc * 64 + ni * 16 + fr;
            Cs[row * 264 + col] = (short)f2bf(acc[mi][ni][r] * dvs[h * 64 + row]);
          }
    }
    __syncthreads();
    int orow = t >> 3, o8 = t & 7;       // 8 threads/row; each owns one 32-col slice segment
    int grow = m0 + h * 64 + orow;
    if (grow < M){
      const short* src = &Cs[orow * 264 + o8 * 32];
      unsigned short* dst = C + (size_t)o8 * SLICE_ELEMS + (size_t)grow * 32;
      v8s v0 = *(const v8s*)(src);
      v8s v1 = *(const v8s*)(src + 8);
      v8s v2 = *(const v8s*)(src + 16);
      v8s v3 = *(const v8s*)(src + 24);
      *(v8s*)(dst) = v0;
      *(v8s*)(dst + 8) = v1;
      *(v8s*)(dst + 16) = v2;
      *(v8s*)(dst + 24) = v3;
    }
  }
}

// ---------------- layer-2 GEMM: 128x256 tile, 512 threads, BN+LN fused into A-staging; writes h1 byproduct ----------------
__global__ __launch_bounds__(512) void gemm2_k(const unsigned short* gB,
                                               const float* Sg, const float* Qg,
                                               const float* bng, const float* bnb,
                                               const float* lng, const float* lnb,
                                               const unsigned short* Bt, const float* dinv,
                                               unsigned short* C, unsigned short* h1, int M){
  __shared__ __align__(16) short smem[16896];  // As[128][40]+Bs[256][40]=15360; Cs[64][264]=16896 aliases
  __shared__ float scs[256], shs[256], lgs[256], lbs[256], muS[128], rsS[128], dvs[128];
  short* As = smem;
  short* Bs = smem + 128 * 40;
  int t = threadIdx.x;
  int m0 = blockIdx.x * 128;
  int lane = t & 63, w = t >> 6;
  int wr = w >> 2, wc = w & 3;
  int fr = lane & 15, quad = lane >> 4;
  if (t < 128) dvs[t] = (m0 + t < M) ? dinv[m0 + t] : 0.0f;
  if (t < 256){
    const float invN = 1.0f / N_NODES;
    float mu = Sg[t] * invN;
    float rs = rsqrtf(Qg[t] * invN - mu * mu + BN_EPS);
    float s = bng[t] * rs;
    scs[t] = s; shs[t] = bnb[t] - s * mu;
    lgs[t] = lng[t]; lbs[t] = lnb[t];
  }
  __syncthreads();
  // phase 1: per-row LN stats over BN-transformed values (4 threads/row x 128 rows, 64 cols each)
  {
    int r = t >> 2, q = t & 3;
    int grow = m0 + r;
    float sum = 0.f, sq = 0.f;
    if (grow < M){
      #pragma unroll
      for (int j = 0; j < 8; ++j){
        int c = q * 64 + j * 8;
        uint4 u = *(const uint4*)(gB + (size_t)grow * H_DIM + c);
        float4 s0 = *(const float4*)(&scs[c]);
        float4 s1 = *(const float4*)(&scs[c + 4]);
        float4 h0 = *(const float4*)(&shs[c]);
        float4 h4 = *(const float4*)(&shs[c + 4]);
        float v0 = s0.x * bflo(u.x) + h0.x;
        float v1 = s0.y * bfhi(u.x) + h0.y;
        float v2 = s0.z * bflo(u.y) + h0.z;
        float v3 = s0.w * bfhi(u.y) + h0.w;
        float v4 = s1.x * bflo(u.z) + h4.x;
        float v5 = s1.y * bfhi(u.z) + h4.y;
        float v6 = s1.z * bflo(u.w) + h4.z;
        float v7 = s1.w * bfhi(u.w) + h4.w;
        sum += v0+v1+v2+v3+v4+v5+v6+v7;
        sq  += v0*v0+v1*v1+v2*v2+v3*v3+v4*v4+v5*v5+v6*v6+v7*v7;
      }
    }
    sum += __shfl_xor(sum, 1, 64); sum += __shfl_xor(sum, 2, 64);
    sq  += __shfl_xor(sq, 1, 64);  sq  += __shfl_xor(sq, 2, 64);
    if (q == 0){
      float mu = sum * (1.0f / H_DIM);
      float var = sq * (1.0f / H_DIM) - mu * mu;
      muS[r] = mu;
      rsS[r] = rsqrtf(var + LN_EPS);
    }
  }
  v4f acc[4][4] = {};
  int ar = t >> 2, aq = t & 3;           // A staging: 128 rows x 4 col-quarters
  int br = t >> 1, bh = t & 1;           // B staging: 256 rows x 2 halves
  for (int k0 = 0; k0 < H_DIM; k0 += 32){
    __syncthreads();
    // A-staging: read gbuf chunk, apply BN+LN, pack bf16 into As and write h1
    {
      int arow = m0 + ar;
      uint4 av = {0,0,0,0};
      if (arow < M){
        int c = k0 + aq * 8;
        uint4 u = *(const uint4*)(gB + (size_t)arow * H_DIM + c);
        float mu = muS[ar], rs = rsS[ar];
        float4 s0 = *(const float4*)(&scs[c]);
        float4 s1 = *(const float4*)(&scs[c + 4]);
        float4 h0 = *(const float4*)(&shs[c]);
        float4 h4 = *(const float4*)(&shs[c + 4]);
        float4 g0 = *(const float4*)(&lgs[c]);
        float4 g1 = *(const float4*)(&lgs[c + 4]);
        float4 b0 = *(const float4*)(&lbs[c]);
        float4 b1 = *(const float4*)(&lbs[c + 4]);
        float y0 = g0.x * ((s0.x * bflo(u.x) + h0.x) - mu) * rs + b0.x;
        float y1 = g0.y * ((s0.y * bfhi(u.x) + h0.y) - mu) * rs + b0.y;
        float y2 = g0.z * ((s0.z * bflo(u.y) + h0.z) - mu) * rs + b0.z;
        float y3 = g0.w * ((s0.w * bfhi(u.y) + h0.w) - mu) * rs + b0.w;
        float y4 = g1.x * ((s1.x * bflo(u.z) + h4.x) - mu) * rs + b1.x;
        float y5 = g1.y * ((s1.y * bfhi(u.z) + h4.y) - mu) * rs + b1.y;
        float y6 = g1.z * ((s1.z * bflo(u.w) + h4.z) - mu) * rs + b1.z;
        float y7 = g1.w * ((s1.w * bfhi(u.w) + h4.w) - mu) * rs + b1.w;
        av.x = pack2(y0, y1); av.y = pack2(y2, y3);
        av.z = pack2(y4, y5); av.w = pack2(y6, y7);
        *(uint4*)(h1 + (size_t)arow * H_DIM + (k0 + aq * 8)) = av;
      }
      *(uint4*)(&As[ar * 40 + aq * 8]) = av;
    }
    {
      const unsigned short* bp = Bt + (size_t)br * H_DIM + k0 + bh * 16;
      uint4 b0 = *(const uint4*)(bp);
      uint4 b1 = *(const uint4*)(bp + 8);
      *(uint4*)(&Bs[br * 40 + bh * 16]) = b0;
      *(uint4*)(&Bs[br * 40 + bh * 16 + 8]) = b1;
    }
    __syncthreads();
    v8s af[4], bf[4];
    #pragma unroll
    for (int mi = 0; mi < 4; ++mi)
      af[mi] = *(const v8s*)(&As[(wr * 64 + mi * 16 + fr) * 40 + quad * 8]);
    #pragma unroll
    for (int ni = 0; ni < 4; ++ni)
      bf[ni] = *(const v8s*)(&Bs[(wc * 64 + ni * 16 + fr) * 40 + quad * 8]);
    #pragma unroll
    for (int mi = 0; mi < 4; ++mi)
      #pragma unroll
      for (int ni = 0; ni < 4; ++ni)
        acc[mi][ni] = __builtin_amdgcn_mfma_f32_16x16x32_bf16(af[mi], bf[ni], acc[mi][ni], 0, 0, 0);
  }
  // epilogue in two 64-row halves; Cs aliases staging LDS
  short* Cs = smem; // [64][264]
  #pragma unroll
  for (int h = 0; h < 2; ++h){
    __syncthreads();
    if (wr == h){
      #pragma unroll
      for (int mi = 0; mi < 4; ++mi)
        #pragma unroll
        for (int ni = 0; ni < 4; ++ni)
          #pragma unroll
          for (int r = 0; r < 4; ++r){
            int row = mi * 16 + quad * 4 + r;
            int col = wc * 64 + ni * 16 + fr;
            Cs[row * 264 + col] = (short)f2bf(acc[mi][ni][r] * dvs[h * 64 + row]);
          }
    }
    __syncthreads();
    int orow = t >> 3, o8 = t & 7;
    int grow = m0 + h * 64 + orow;
    if (grow < M){
      const short* src = &Cs[orow * 264 + o8 * 32];
      unsigned short* dst = C + (size_t)o8 * SLICE_ELEMS + (size_t)grow * 32;
      v8s v0 = *(const v8s*)(src);
      v8s v1 = *(const v8s*)(src + 8);
      v8s v2 = *(const v8s*)(src + 16);
      v8s v3 = *(const v8s*)(src + 24);
      *(v8s*)(dst) = v0;
      *(v8s*)(dst + 8) = v1;
      *(v8s*)(dst + 16) = v2;
      *(v8s*)(dst + 24) = v3;
    }
  }
}

#define ACCP(u, A) { v2f d_ = {bflo(u), bfhi(u)}; A += d_; }
#define ACC8(vv) ACCP(vv.x, A0) ACCP(vv.y, A1) ACCP(vv.z, A2) ACCP(vv.w, A3)

// ---------------- edge aggregation: 4 threads/node, uint4 gathers, 64 nodes/block (256 threads),
//                  LDS edge staging, packed f32 accumulate; BN col-sums folded via atomics ----------------
__global__ __launch_bounds__(256, 4) void agg_k(const unsigned short* hs, const int* offsets,
                                                const unsigned short* edges, const int* perm,
                                                const float* dinv, const float* bias,
                                                unsigned short* g, float* Sg, float* Qg){
  __shared__ unsigned eds32[EDGE_CHUNK / 2];
  __shared__ float wps[4][4][16];
  int t = threadIdx.x;
  int lane = t & 63;
  int wv = t >> 6;
  int slice = blockIdx.x & 7;
  int l4 = lane & 3;
  int grp = blockIdx.x >> 3;
  int nb = grp * 64;
  int idx = nb + (t >> 2);
  int lastn = min(nb + 64, N_NODES);
  int blk0 = offsets[nb];
  int base = blk0 & ~1;
  int blkN = offsets[lastn];
  const unsigned* gsrc = (const unsigned*)(edges + base);
  int nu = min((blkN - base + 1) >> 1, EDGE_CHUNK / 2);
  for (int i = t; i < nu; i += 256)
    eds32[i] = gsrc[i];
  __syncthreads();
  bool act = idx < N_NODES;
  int node = act ? perm[idx] : 0;
  float dvv = act ? dinv[node] : 0.f;
  const uint4* hb4 = (const uint4*)(hs + (size_t)slice * SLICE_ELEMS);
  float4 bb0 = *(const float4*)(bias + slice * 32 + l4 * 8);
  float4 bb1 = *(const float4*)(bias + slice * 32 + l4 * 8 + 4);
  uint4 sv = hb4[(size_t)node * 4 + l4];
  v2f A0 = {bflo(sv.x), bfhi(sv.x)};
  v2f A1 = {bflo(sv.y), bfhi(sv.y)};
  v2f A2 = {bflo(sv.z), bfhi(sv.z)};
  v2f A3 = {bflo(sv.w), bfhi(sv.w)};
  int e  = act ? offsets[idx] : 0;
  int e1 = act ? offsets[idx + 1] : 0;
  if ((e & 1) && e < e1){
    int ru = (e - base) >> 1;
    unsigned d = (ru < EDGE_CHUNK / 2) ? eds32[ru] : gsrc[ru];
    uint4 vv = hb4[(size_t)(d >> 16) * 4 + l4];
    ACC8(vv);
    ++e;
  }
  for (; e + 16 <= e1; e += 16){
    int ru = (e - base) >> 1;
    unsigned dd[8];
    if (ru + 8 <= EDGE_CHUNK / 2){
      #pragma unroll
      for (int j = 0; j < 8; ++j) dd[j] = eds32[ru + j];
    } else {
      #pragma unroll
      for (int j = 0; j < 8; ++j) dd[j] = gsrc[ru + j];
    }
    uint4 v[16];
    #pragma unroll
    for (int j = 0; j < 8; ++j){
      v[2*j]   = hb4[(size_t)(dd[j] & 0xffffu) * 4 + l4];
      v[2*j+1] = hb4[(size_t)(dd[j] >> 16)     * 4 + l4];
    }
    #pragma unroll
    for (int j = 0; j < 16; ++j){ ACC8(v[j]); }
  }
  if (e + 8 <= e1){
    int ru = (e - base) >> 1;
    unsigned dd[4];
    if (ru + 4 <= EDGE_CHUNK / 2){
      #pragma unroll
      for (int j = 0; j < 4; ++j) dd[j] = eds32[ru + j];
    } else {
      #pragma unroll
      for (int j = 0; j < 4; ++j) dd[j] = gsrc[ru + j];
    }
    uint4 v[8];
    #pragma unroll
    for (int j = 0; j < 4; ++j){
      v[2*j]   = hb4[(size_t)(dd[j] & 0xffffu) * 4 + l4];
      v[2*j+1] = hb4[(size_t)(dd[j] >> 16)     * 4 + l4];
    }
    #pragma unroll
    for (int j = 0; j < 8; ++j){ ACC8(v[j]); }
    e += 8;
  }
  if (e + 4 <= e1){
    int ru = (e - base) >> 1;
    unsigned dd0, dd1;
    if (ru + 2 <= EDGE_CHUNK / 2){
      dd0 = eds32[ru]; dd1 = eds32[ru + 1];
    } else {
      dd0 = gsrc[ru]; dd1 = gsrc[ru + 1];
    }
    uint4 v[4];
    v[0] = hb4[(size_t)(dd0 & 0xffffu) * 4 + l4];
    v[1] = hb4[(size_t)(dd0 >> 16)     * 4 + l4];
    v[2] = hb4[(size_t)(dd1 & 0xffffu) * 4 + l4];
    v[3] = hb4[(size_t)(dd1 >> 16)     * 4 + l4];
    #pragma unroll
    for (int j = 0; j < 4; ++j){ ACC8(v[j]); }
    e += 4;
  }
  for (; e < e1; ++e){
    int r = e - base;
    unsigned d = ((r >> 1) < EDGE_CHUNK / 2) ? eds32[r >> 1] : gsrc[r >> 1];
    unsigned s = (r & 1) ? (d >> 16) : (d & 0xffffu);
    uint4 vv = hb4[(size_t)s * 4 + l4];
    ACC8(vv);
  }
  float y0 = act ? fmaxf(dvv * A0.x + bb0.x, 0.f) : 0.f;
  float y1 = act ? fmaxf(dvv * A0.y + bb0.y, 0.f) : 0.f;
  float y2 = act ? fmaxf(dvv * A1.x + bb0.z, 0.f) : 0.f;
  float y3 = act ? fmaxf(dvv * A1.y + bb0.w, 0.f) : 0.f;
  float y4 = act ? fmaxf(dvv * A2.x + bb1.x, 0.f) : 0.f;
  float y5 = act ? fmaxf(dvv * A2.y + bb1.y, 0.f) : 0.f;
  float y6 = act ? fmaxf(dvv * A3.x + bb1.z, 0.f) : 0.f;
  float y7 = act ? fmaxf(dvv * A3.y + bb1.w, 0.f) : 0.f;
  if (act){
    v4u o;
    o.x = pack2(y0, y1); o.y = pack2(y2, y3);
    o.z = pack2(y4, y5); o.w = pack2(y6, y7);
    __builtin_nontemporal_store(o, (v4u*)(g + (size_t)node * H_DIM + slice * 32 + l4 * 8));
  }
  float q0 = y0*y0, q1 = y1*y1, q2 = y2*y2, q3 = y3*y3;
  float q4 = y4*y4, q5 = y5*y5, q6 = y6*y6, q7 = y7*y7;
  #pragma unroll
  for (int m = 4; m < 64; m <<= 1){
    y0 += __shfl_xor(y0, m, 64); y1 += __shfl_xor(y1, m, 64);
    y2 += __shfl_xor(y2, m, 64); y3 += __shfl_xor(y3, m, 64);
    y4 += __shfl_xor(y4, m, 64); y5 += __shfl_xor(y5, m, 64);
    y6 += __shfl_xor(y6, m, 64); y7 += __shfl_xor(y7, m, 64);
    q0 += __shfl_xor(q0, m, 64); q1 += __shfl_xor(q1, m, 64);
    q2 += __shfl_xor(q2, m, 64); q3 += __shfl_xor(q3, m, 64);
    q4 += __shfl_xor(q4, m, 64); q5 += __shfl_xor(q5, m, 64);
    q6 += __shfl_xor(q6, m, 64); q7 += __shfl_xor(q7, m, 64);
  }
  if (lane < 4){
    wps[wv][lane][0] = y0; wps[wv][lane][1] = y1; wps[wv][lane][2] = y2; wps[wv][lane][3] = y3;
    wps[wv][lane][4] = y4; wps[wv][lane][5] = y5; wps[wv][lane][6] = y6; wps[wv][lane][7] = y7;
    wps[wv][lane][8] = q0; wps[wv][lane][9] = q1; wps[wv][lane][10] = q2; wps[wv][lane][11] = q3;
    wps[wv][lane][12] = q4; wps[wv][lane][13] = q5; wps[wv][lane][14] = q6; wps[wv][lane][15] = q7;
  }
  __syncthreads();
  if (t < 64){
    int tl = t >> 4, ti = t & 15;
    float v = wps[0][tl][ti] + wps[1][tl][ti] + wps[2][tl][ti] + wps[3][tl][ti];
    int col32 = tl * 8 + (ti & 7);
    if (ti < 8) atomicAdd(&Sg[slice * 32 + col32], v);
    else        atomicAdd(&Qg[slice * 32 + col32], v);
  }
}

// ---------------- layer 2 apply + residual + output GEMM; BN coeffs derived inline ----------------
__global__ __launch_bounds__(256) void apply2_k(const unsigned short* g,
                                                const float* Sg, const float* Qg,
                                                const float* bng, const float* bnb,
                                                const float* lng, const float* lnb,
                                                const unsigned short* h1, const float* Wout,
                                                const float* bout, float* out){
  int t = threadIdx.x;
  int lane32 = t & 31;
  int row = blockIdx.x * 8 + (t >> 5);
  if (row >= N_NODES) return;
  int c = lane32 * 8;
  const float invN = 1.0f / N_NODES;
  float4 S0 = *(const float4*)(Sg + c), S1 = *(const float4*)(Sg + c + 4);
  float4 Q0 = *(const float4*)(Qg + c), Q1 = *(const float4*)(Qg + c + 4);
  float4 G0 = *(const float4*)(bng + c), G1 = *(const float4*)(bng + c + 4);
  float4 B0 = *(const float4*)(bnb + c), B1 = *(const float4*)(bnb + c + 4);
  float Sa[8] = {S0.x,S0.y,S0.z,S0.w,S1.x,S1.y,S1.z,S1.w};
  float Qa[8] = {Q0.x,Q0.y,Q0.z,Q0.w,Q1.x,Q1.y,Q1.z,Q1.w};
  float Ga[8] = {G0.x,G0.y,G0.z,G0.w,G1.x,G1.y,G1.z,G1.w};
  float Ba[8] = {B0.x,B0.y,B0.z,B0.w,B1.x,B1.y,B1.z,B1.w};
  float scv[8], shv[8];
  #pragma unroll
  for (int j = 0; j < 8; ++j){
    float mu = Sa[j] * invN;
    float rs = rsqrtf(Qa[j] * invN - mu * mu + BN_EPS);
    float s = Ga[j] * rs;
    scv[j] = s; shv[j] = Ba[j] - s * mu;
  }
  uint4 u = *(const uint4*)(g + (size_t)row * H_DIM + c);
  float v0 = scv[0] * bflo(u.x) + shv[0];
  float v1 = scv[1] * bfhi(u.x) + shv[1];
  float v2 = scv[2] * bflo(u.y) + shv[2];
  float v3 = scv[3] * bfhi(u.y) + shv[3];
  float v4 = scv[4] * bflo(u.z) + shv[4];
  float v5 = scv[5] * bfhi(u.z) + shv[5];
  float v6 = scv[6] * bflo(u.w) + shv[6];
  float v7 = scv[7] * bfhi(u.w) + shv[7];
  float sum = v0+v1+v2+v3+v4+v5+v6+v7;
  float sq  = v0*v0+v1*v1+v2*v2+v3*v3+v4*v4+v5*v5+v6*v6+v7*v7;
  #pragma unroll
  for (int m = 1; m < 32; m <<= 1){ sum += __shfl_xor(sum, m, 64); sq += __shfl_xor(sq, m, 64); }
  float mu = sum * (1.0f / H_DIM);
  float var = sq * (1.0f / H_DIM) - mu * mu;
  float rs = rsqrtf(var + LN_EPS);
  float4 g40 = *(const float4*)(lng + c);
  float4 g41 = *(const float4*)(lng + c + 4);
  float4 b40 = *(const float4*)(lnb + c);
  float4 b41 = *(const float4*)(lnb + c + 4);
  uint4 hr = *(const uint4*)(h1 + (size_t)row * H_DIM + c);
  float y0 = g40.x * (v0 - mu) * rs + b40.x + bflo(hr.x);
  float y1 = g40.y * (v1 - mu) * rs + b40.y + bfhi(hr.x);
  float y2 = g40.z * (v2 - mu) * rs + b40.z + bflo(hr.y);
  float y3 = g40.w * (v3 - mu) * rs + b40.w + bfhi(hr.y);
  float y4 = g41.x * (v4 - mu) * rs + b41.x + bflo(hr.z);
  float y5 = g41.y * (v5 - mu) * rs + b41.y + bfhi(hr.z);
  float y6 = g41.z * (v6 - mu) * rs + b41.z + bflo(hr.w);
  float y7 = g41.w * (v7 - mu) * rs + b41.w + bfhi(hr.w);
  float4 w0 = *(const float4*)(Wout + c * 2);
  float4 w1 = *(const float4*)(Wout + c * 2 + 4);
  float4 w2 = *(const float4*)(Wout + c * 2 + 8);
  float4 w3 = *(const float4*)(Wout + c * 2 + 12);
  float o0 = y0*w0.x + y1*w0.z + y2*w1.x + y3*w1.z + y4*w2.x + y5*w2.z + y6*w3.x + y7*w3.z;
  float o1 = y0*w0.y + y1*w0.w + y2*w1.y + y3*w1.w + y4*w2.y + y5*w2.w + y6*w3.y + y7*w3.w;
  #pragma unroll
  for (int m = 1; m < 32; m <<= 1){ o0 += __shfl_xor(o0, m, 64); o1 += __shfl_xor(o1, m, 64); }
  if (lane32 == 0){
    out[(size_t)row * 2 + 0] = o0 + bout[0];
    out[(size_t)row * 2 + 1] = o1 + bout[1];
  }
}

extern "C" void kernel_launch(void* const* d_in, const int* in_sizes, int n_in,
                              void* d_out, int out_size, void* d_ws, size_t ws_size,
                              hipStream_t stream) {
  const float* x    = (const float*)d_in[0];
  const int*   ei   = (const int*)d_in[1];
  const float* fs   = (const float*)d_in[2];
  const float* fb   = (const float*)d_in[3];
  const float* bn0g = (const float*)d_in[4];
  const float* bn0b = (const float*)d_in[5];
  const float* W1   = (const float*)d_in[6];
  const float* b1   = (const float*)d_in[7];
  const float* bn1g = (const float*)d_in[8];
  const float* bn1b = (const float*)d_in[9];
  const float* ln1g = (const float*)d_in[10];
  const float* ln1b = (const float*)d_in[11];
  const float* W2   = (const float*)d_in[12];
  const float* b2   = (const float*)d_in[13];
  const float* bn2g = (const float*)d_in[14];
  const float* bn2b = (const float*)d_in[15];
  const float* ln2g = (const float*)d_in[16];
  const float* ln2b = (const float*)d_in[17];
  const float* Wout = (const float*)d_in[18];
  const float* bout = (const float*)d_in[19];
  float* out = (float*)d_out;

  char* w = (char*)d_ws;
  float* bn0S  = (float*)(w + 0);          // [8][128] -> 4096
  float* bn0Q  = (float*)(w + 4096);       // -> 8192
  int*   ghist  = (int*)(w + 8192);        // 196 ints -> 8976
  int*   gcursor= (int*)(w + 8976);        // 196 ints -> 9760
  float* Sg1   = (float*)(w + 9760);       // 1024 -> 10784
  float* Qg1   = (float*)(w + 10784);      // -> 11808
  float* Sg2   = (float*)(w + 11808);      // -> 12832
  float* Qg2   = (float*)(w + 12832);      // -> 13856
  const size_t ZERO_BYTES = 13856;
  float* dinv  = (float*)(w + 211584);     // 200000 -> 411584
  int*   offs  = (int*)(w + 411584);       // 200004 -> pad 611712
  int*   perm  = (int*)(w + 611712);       // 200000 -> 811712
  unsigned short* edges = (unsigned short*)(w + 1011712); // 1600000 -> 2611712
  unsigned short* W1t  = (unsigned short*)(w + 15411712);  // -> 15477248
  unsigned short* W2t  = (unsigned short*)(w + 15477248);  // -> 15608320
  unsigned short* hlin = (unsigned short*)(w + 15608320);  // 25.6 MB -> 41208320
  unsigned*       ebuf = (unsigned*)(w + 15608320);        // aliases hlin (3.2 MB, dead before gemm1)
  unsigned short* gbuf = (unsigned short*)(w + 41208320);  // 25.6 MB -> 66808320
  unsigned short* h1   = (unsigned short*)(w + 66808320);  // 25.6 MB -> 92408320

  (void)in_sizes; (void)n_in; (void)out_size; (void)ws_size;

  hipMemsetAsync(d_ws, 0, ZERO_BYTES, stream);

  // preprocessing: bucketed counting sort, fused per-bucket degree-sort+scatter
  bn0r1_k<<<BN0_BLOCKS + RCHUNKS, 256, 0, stream>>>(ei, x, fs, fb, bn0S, bn0Q, ghist);
  r3_k<<<RCHUNKS, 256, 0, stream>>>(ei, ghist, gcursor, ebuf);
  sortprep_k<<<NBKT + TR_BLOCKS, 256, 0, stream>>>(
      ebuf, ghist, perm, offs, dinv, edges, W1, W2, W1t, W2t);

  int g1grid = (N_NODES + 127) / 128;
  int agg_blocks = NBLK2 * 8;

  // ---- layer 1 (BN0 apply fused into gemm1 A-staging; BN1 col-sums folded into agg atomics) ----
  gemm1_k<<<g1grid, 512, 0, stream>>>(x, bn0S, bn0Q, fs, fb, bn0g, bn0b, W1t, dinv, hlin, N_NODES);
  agg_k<<<agg_blocks, 256, 0, stream>>>(hlin, offs, edges, perm, dinv, b1, gbuf, Sg1, Qg1);

  // ---- layer 2 (BN1+LN1 fused into gemm2 A-staging, 128-row tile; h1 byproduct) ----
  gemm2_k<<<g1grid, 512, 0, stream>>>(gbuf, Sg1, Qg1, bn1g, bn1b, ln1g, ln1b, W2t, dinv, hlin, h1, N_NODES);
  agg_k<<<agg_blocks, 256, 0, stream>>>(hlin, offs, edges, perm, dinv, b2, gbuf, Sg2, Qg2);
  apply2_k<<<(N_NODES + 7) / 8, 256, 0, stream>>>(gbuf, Sg2, Qg2, bn2g, bn2b, ln2g, ln2b, h1, Wout, bout, out);
}

// Round 13
// 329.482 us; speedup vs baseline: 1.0284x; 1.0284x over previous
//
#include <hip/hip_runtime.h>
#include <hip/hip_bf16.h>
#include <stdint.h>

#define N_NODES 50000
#define N_EDGES 800000
#define D_IN    128
#define H_DIM   256
#define BN_EPS  1e-5f
#define LN_EPS  1e-5f
#define NBLK2 782      // ceil(50000/64) node-groups for agg (64 nodes/block)
#define SLICE_ELEMS ((size_t)N_NODES * 32)
#define EDGE_CHUNK 4096   // edges cached in LDS per agg block
#define BN0_BLOCKS 1024
#define TR_BLOCKS 256     // 65536/256
#define NBKT 196          // coarse buckets: dst >> 8
#define CHUNK 2048        // edges per radix block
#define RCHUNKS 391       // ceil(800000/2048)

typedef float v4f __attribute__((ext_vector_type(4)));
typedef float v2f __attribute__((ext_vector_type(2)));
typedef short v8s __attribute__((ext_vector_type(8)));
typedef unsigned v4u __attribute__((ext_vector_type(4)));

__device__ __forceinline__ float bflo(unsigned u){ return __uint_as_float(u << 16); }
__device__ __forceinline__ float bfhi(unsigned u){ return __uint_as_float(u & 0xffff0000u); }
__device__ __forceinline__ unsigned short f2bf(float f){
  unsigned u = __float_as_uint(f);
  u += 0x7fffu + ((u >> 16) & 1u);
  return (unsigned short)(u >> 16);
}
__device__ __forceinline__ unsigned pack2(float a, float b){
  return (unsigned)f2bf(a) | ((unsigned)f2bf(b) << 16);
}

__device__ __forceinline__ int block_excl_scan(int v){
  int t = threadIdx.x;
  int lane = t & 63, w = t >> 6;
  int inc = v;
  #pragma unroll
  for (int m = 1; m < 64; m <<= 1){
    int o = __shfl_up(inc, m, 64);
    if (lane >= m) inc += o;
  }
  __shared__ int wsum[4];
  if (lane == 63) wsum[w] = inc;
  __syncthreads();
  int base = 0;
  #pragma unroll
  for (int j = 0; j < 4; ++j) if (j < w) base += wsum[j];
  return base + inc - v;  // exclusive
}

// ---------------- fused: BN0 stats (blocks 0..1023, 8 rotation buffers) || coarse bucket histogram ----------------
__global__ __launch_bounds__(256) void bn0r1_k(const int* ei, const float* x,
                                               const float* fs, const float* fb,
                                               float* S, float* Q, int* ghist){
  int b = blockIdx.x, t = threadIdx.x;
  if (b >= BN0_BLOCKS){
    __shared__ int lh[NBKT];
    int b2 = b - BN0_BLOCKS;
    for (int i = t; i < NBKT; i += 256) lh[i] = 0;
    __syncthreads();
    int e0 = b2 * CHUNK;
    int n = min(CHUNK, N_EDGES - e0);
    for (int i = t; i < n; i += 256)
      atomicAdd(&lh[ei[N_EDGES + e0 + i] >> 8], 1);
    __syncthreads();
    if (t < NBKT && lh[t] > 0) atomicAdd(&ghist[t], lh[t]);
    return;
  }
  int cl = t & 31, rg = t >> 5;
  int c = cl * 4;
  float4 fs4 = *(const float4*)(fs + c);
  float4 fb4 = *(const float4*)(fb + c);
  float s0=0,s1=0,s2=0,s3=0,q0=0,q1=0,q2=0,q3=0;
  for (int row = b * 8 + rg; row < N_NODES; row += BN0_BLOCKS * 8){
    float4 xv = *(const float4*)(x + (size_t)row * D_IN + c);
    float v0 = xv.x * fs4.x + fb4.x;
    float v1 = xv.y * fs4.y + fb4.y;
    float v2 = xv.z * fs4.z + fb4.z;
    float v3 = xv.w * fs4.w + fb4.w;
    s0 += v0; s1 += v1; s2 += v2; s3 += v3;
    q0 += v0*v0; q1 += v1*v1; q2 += v2*v2; q3 += v3*v3;
  }
  __shared__ float red[256][8];
  red[t][0]=s0; red[t][1]=s1; red[t][2]=s2; red[t][3]=s3;
  red[t][4]=q0; red[t][5]=q1; red[t][6]=q2; red[t][7]=q3;
  __syncthreads();
  float* Sr = S + (b & 7) * D_IN;
  float* Qr = Q + (b & 7) * D_IN;
  if (t < 32){
    float a[8];
    #pragma unroll
    for (int i = 0; i < 8; ++i) a[i] = red[t][i];
    for (int j = 1; j < 8; ++j)
      #pragma unroll
      for (int i = 0; i < 8; ++i) a[i] += red[t + 32*j][i];
    #pragma unroll
    for (int i = 0; i < 4; ++i){ atomicAdd(&Sr[t*4+i], a[i]); atomicAdd(&Qr[t*4+i], a[4+i]); }
  }
}

// ---------------- coarse scatter: edges -> ebuf bucketed by dst>>8 (LDS atomics; in-block ghist scan) ----------------
__global__ __launch_bounds__(256) void r3_k(const int* ei, const int* ghist, int* gcursor, unsigned* ebuf){
  __shared__ unsigned short dstS[CHUNK];
  __shared__ int lh[NBKT], cb[NBKT], sbb[NBKT];
  int t = threadIdx.x;
  int v = (t < NBKT) ? ghist[t] : 0;
  int epre = block_excl_scan(v);
  if (t < NBKT){ sbb[t] = epre; lh[t] = 0; }
  __syncthreads();
  int e0 = blockIdx.x * CHUNK;
  int n = min(CHUNK, N_EDGES - e0);
  for (int i = t; i < n; i += 256){
    int d = ei[N_EDGES + e0 + i];
    dstS[i] = (unsigned short)d;
    atomicAdd(&lh[d >> 8], 1);
  }
  __syncthreads();
  if (t < NBKT && lh[t] > 0) cb[t] = sbb[t] + atomicAdd(&gcursor[t], lh[t]);
  __syncthreads();
  if (t < NBKT) lh[t] = 0;
  __syncthreads();
  for (int i = t; i < n; i += 256){
    int d = dstS[i];
    int bkt = d >> 8;
    int r = atomicAdd(&lh[bkt], 1);
    unsigned src = (unsigned)ei[e0 + i];
    ebuf[cb[bkt] + r] = ((unsigned)(d & 255) << 16) | src;
  }
}

// ---------------- fused: per-bucket degree sort + edge scatter (blocks 0..195) || weight transpose ----------------
__global__ __launch_bounds__(256) void sortprep_k(const unsigned* ebuf, const int* ghist,
                                                  int* perm, int* offs, float* dinv,
                                                  unsigned short* edges,
                                                  const float* W1, const float* W2,
                                                  unsigned short* W1t, unsigned short* W2t){
  int b = blockIdx.x, t = threadIdx.x;
  if (b < NBKT){
    __shared__ int h[256], dh[128], ep_s[128], W_s[128], lc[128], curs[256], sbb[NBKT + 1];
    int gv = (t < NBKT) ? ghist[t] : 0;
    int gpre = block_excl_scan(gv);
    if (t < NBKT) sbb[t] = gpre;
    if (t == NBKT - 1) sbb[NBKT] = gpre + gv;
    h[t] = 0;
    if (t < 128){ dh[t] = 0; lc[t] = 0; }
    __syncthreads();
    int lo = sbb[b], hi = sbb[b + 1];
    for (int i = lo + t; i < hi; i += 256)
      atomicAdd(&h[(ebuf[i] >> 16) & 255], 1);
    __syncthreads();
    int node = b * 256 + t;
    bool valid = node < N_NODES;
    int deg = valid ? h[t] : 0;
    if (valid) atomicAdd(&dh[min(deg, 127)], 1);
    __syncthreads();
    int cv = (t < 128) ? dh[t] : 0;
    int e1 = block_excl_scan(cv);
    __syncthreads();
    int e2 = block_excl_scan((t < 128) ? cv * t : 0);
    __syncthreads();
    if (t < 128){ ep_s[t] = e1; W_s[t] = e2; }
    __syncthreads();
    if (valid){
      int bin = min(deg, 127);
      int r = atomicAdd(&lc[bin], 1);
      int pl = ep_s[bin] + r;              // local (within-bucket) rank
      int pos = b * 256 + pl;              // global position: buckets are contiguous
      int off = lo + W_s[bin] + (pl - ep_s[bin]) * deg;  // all nodes in bin have degree == bin
      perm[pos] = node;
      offs[pos] = off;
      dinv[node] = rsqrtf((float)deg + 1.0f);
      curs[t] = off;                        // scatter cursor, indexed by node low byte (== t)
    }
    __syncthreads();
    for (int i = lo + t; i < hi; i += 256){
      unsigned u = ebuf[i];
      int l8 = (u >> 16) & 255;
      int pos = atomicAdd(&curs[l8], 1);
      edges[pos] = (unsigned short)(u & 0xffffu);
    }
    if (b == 0 && t == 0) offs[N_NODES] = N_EDGES;
    return;
  }
  int i = (b - NBKT) * 256 + t;
  if (i < D_IN * H_DIM){
    int r = i / H_DIM, c = i % H_DIM;
    W1t[c * D_IN + r] = f2bf(W1[i]);
  }
  if (i < H_DIM * H_DIM){
    int r = i / H_DIM, c = i % H_DIM;
    W2t[c * H_DIM + r] = f2bf(W2[i]);
  }
}

// ---------------- layer-1 GEMM: 128x256 tile, 512 threads (8 waves, 2Mx4N), BN0 fused into A-staging ----------------
__global__ __launch_bounds__(512) void gemm1_k(const float* x, const float* S, const float* Q,
                                               const float* fs, const float* fb,
                                               const float* gg, const float* bb,
                                               const unsigned short* Bt, const float* dinv,
                                               unsigned short* C, int M){
  __shared__ __align__(16) short smem[16896]; // staging: As[128][40]=5120 + Bs[256][40]=10240 shorts; epilogue Cs[64][264]=16896 aliases
  __shared__ float ac[128], cc[128], dvs[128];
  short* As = smem;
  short* Bs = smem + 128 * 40;
  int t = threadIdx.x;
  int m0 = blockIdx.x * 128;
  int lane = t & 63, w = t >> 6;
  int wr = w >> 2, wc = w & 3;           // wave row-half (2) x col-quarter (4)
  int fr = lane & 15, quad = lane >> 4;
  if (t < 128){
    dvs[t] = (m0 + t < M) ? dinv[m0 + t] : 0.0f;
    float s8 = 0.f, q8 = 0.f;
    #pragma unroll
    for (int rep = 0; rep < 8; ++rep){ s8 += S[rep * D_IN + t]; q8 += Q[rep * D_IN + t]; }
    const float invN = 1.0f / N_NODES;
    float mu = s8 * invN;
    float rs = rsqrtf(q8 * invN - mu * mu + BN_EPS);
    float a = gg[t] * rs * fs[t];
    ac[t] = a;
    cc[t] = gg[t] * rs * (fb[t] - mu) + bb[t];
  }
  __syncthreads();
  v4f acc[4][4] = {};
  int ar = t >> 2, aq = t & 3;           // A staging: 128 rows x 4 col-quarters
  int br = t >> 1, bh = t & 1;           // B staging: 256 rows x 2 halves
  for (int k0 = 0; k0 < D_IN; k0 += 32){
    __syncthreads();
    {
      int arow = m0 + ar;
      int c = k0 + aq * 8;
      float4 xv0 = {0,0,0,0}, xv1 = {0,0,0,0};
      if (arow < M){
        xv0 = *(const float4*)(x + (size_t)arow * D_IN + c);
        xv1 = *(const float4*)(x + (size_t)arow * D_IN + c + 4);
      }
      float4 a0 = *(const float4*)(&ac[c]);
      float4 a1 = *(const float4*)(&ac[c + 4]);
      float4 c0 = *(const float4*)(&cc[c]);
      float4 c1 = *(const float4*)(&cc[c + 4]);
      uint4 o;
      o.x = pack2(a0.x * xv0.x + c0.x, a0.y * xv0.y + c0.y);
      o.y = pack2(a0.z * xv0.z + c0.z, a0.w * xv0.w + c0.w);
      o.z = pack2(a1.x * xv1.x + c1.x, a1.y * xv1.y + c1.y);
      o.w = pack2(a1.z * xv1.z + c1.z, a1.w * xv1.w + c1.w);
      *(uint4*)(&As[ar * 40 + aq * 8]) = o;
    }
    {
      const unsigned short* bp = Bt + (size_t)br * D_IN + k0 + bh * 16;
      uint4 b0 = *(const uint4*)(bp);
      uint4 b1 = *(const uint4*)(bp + 8);
      *(uint4*)(&Bs[br * 40 + bh * 16]) = b0;
      *(uint4*)(&Bs[br * 40 + bh * 16 + 8]) = b1;
    }
    __syncthreads();
    v8s af[4], bf[4];
    #pragma unroll
    for (int mi = 0; mi < 4; ++mi)
      af[mi] = *(const v8s*)(&As[(wr * 64 + mi * 16 + fr) * 40 + quad * 8]);
    #pragma unroll
    for (int ni = 0; ni < 4; ++ni)
      bf[ni] = *(const v8s*)(&Bs[(wc * 64 + ni * 16 + fr) * 40 + quad * 8]);
    #pragma unroll
    for (int mi = 0; mi < 4; ++mi)
      #pragma unroll
      for (int ni = 0; ni < 4; ++ni)
        acc[mi][ni] = __builtin_amdgcn_mfma_f32_16x16x32_bf16(af[mi], bf[ni], acc[mi][ni], 0, 0, 0);
  }
  // epilogue in two 64-row halves; Cs aliases staging LDS
  short* Cs = smem; // [64][264]
  #pragma unroll
  for (int h = 0; h < 2; ++h){
    __syncthreads();
    if (wr == h){
      #pragma unroll
      for (int mi = 0; mi < 4; ++mi)
        #pragma unroll
        for (int ni = 0; ni < 4; ++ni)
          #pragma unroll
          for (int r = 0; r < 4; ++r){
            int row = mi * 16 + quad * 4 + r;
            int col = wc * 64 + ni * 16 + fr;
            Cs[row * 264 + col] = (short)f2bf(acc[mi][ni][r] * dvs[h * 64 + row]);
          }
    }
    __syncthreads();
    int orow = t >> 3, o8 = t & 7;       // 8 threads/row; each owns one 32-col slice segment
    int grow = m0 + h * 64 + orow;
    if (grow < M){
      const short* src = &Cs[orow * 264 + o8 * 32];
      unsigned short* dst = C + (size_t)o8 * SLICE_ELEMS + (size_t)grow * 32;
      v8s v0 = *(const v8s*)(src);
      v8s v1 = *(const v8s*)(src + 8);
      v8s v2 = *(const v8s*)(src + 16);
      v8s v3 = *(const v8s*)(src + 24);
      *(v8s*)(dst) = v0;
      *(v8s*)(dst + 8) = v1;
      *(v8s*)(dst + 16) = v2;
      *(v8s*)(dst + 24) = v3;
    }
  }
}

// ---------------- layer-2 GEMM: gemm_k structure + BN/LN applied during A-staging; writes h1 byproduct ----------------
__global__ __launch_bounds__(256) void gemm2_k(const unsigned short* gB,
                                               const float* Sg, const float* Qg,
                                               const float* bng, const float* bnb,
                                               const float* lng, const float* lnb,
                                               const unsigned short* Bt, const float* dinv,
                                               unsigned short* C, unsigned short* h1, int M){
  __shared__ __align__(16) short smem[16896];  // As[64][40]+Bs[256][40]; Cs[64][264] aliases
  __shared__ float scs[256], shs[256], lgs[256], lbs[256], muS[64], rsS[64], dvs[64];
  short* As = smem;
  short* Bs = smem + 64 * 40;
  int t = threadIdx.x;
  int m0 = blockIdx.x * 64;
  int lane = t & 63, w = t >> 6;
  int fr = lane & 15, quad = lane >> 4;
  if (t < 64) dvs[t] = (m0 + t < M) ? dinv[m0 + t] : 0.0f;
  {
    const float invN = 1.0f / N_NODES;
    float mu = Sg[t] * invN;
    float rs = rsqrtf(Qg[t] * invN - mu * mu + BN_EPS);
    float s = bng[t] * rs;
    scs[t] = s; shs[t] = bnb[t] - s * mu;
    lgs[t] = lng[t]; lbs[t] = lnb[t];
  }
  __syncthreads();
  // phase 1: per-row LN stats over BN-transformed values (4 threads/row, 64 cols each)
  {
    int r = t >> 2, q = t & 3;
    int grow = m0 + r;
    float sum = 0.f, sq = 0.f;
    if (grow < M){
      #pragma unroll
      for (int j = 0; j < 8; ++j){
        int c = q * 64 + j * 8;
        uint4 u = *(const uint4*)(gB + (size_t)grow * H_DIM + c);
        float4 s0 = *(const float4*)(&scs[c]);
        float4 s1 = *(const float4*)(&scs[c + 4]);
        float4 h0 = *(const float4*)(&shs[c]);
        float4 h4 = *(const float4*)(&shs[c + 4]);
        float v0 = s0.x * bflo(u.x) + h0.x;
        float v1 = s0.y * bfhi(u.x) + h0.y;
        float v2 = s0.z * bflo(u.y) + h0.z;
        float v3 = s0.w * bfhi(u.y) + h0.w;
        float v4 = s1.x * bflo(u.z) + h4.x;
        float v5 = s1.y * bfhi(u.z) + h4.y;
        float v6 = s1.z * bflo(u.w) + h4.z;
        float v7 = s1.w * bfhi(u.w) + h4.w;
        sum += v0+v1+v2+v3+v4+v5+v6+v7;
        sq  += v0*v0+v1*v1+v2*v2+v3*v3+v4*v4+v5*v5+v6*v6+v7*v7;
      }
    }
    sum += __shfl_xor(sum, 1, 64); sum += __shfl_xor(sum, 2, 64);
    sq  += __shfl_xor(sq, 1, 64);  sq  += __shfl_xor(sq, 2, 64);
    if (q == 0){
      float mu = sum * (1.0f / H_DIM);
      float var = sq * (1.0f / H_DIM) - mu * mu;
      muS[r] = mu;
      rsS[r] = rsqrtf(var + LN_EPS);
    }
  }
  v4f acc[4][4] = {};
  int sr = t >> 2;
  int sk = (t & 3) << 3;
  for (int k0 = 0; k0 < H_DIM; k0 += 32){
    __syncthreads();
    // A-staging: read gbuf chunk, apply BN+LN, pack bf16 into As and write h1
    {
      int arow = m0 + sr;
      uint4 av = {0,0,0,0};
      if (arow < M){
        int c = k0 + sk;
        uint4 u = *(const uint4*)(gB + (size_t)arow * H_DIM + c);
        float mu = muS[sr], rs = rsS[sr];
        float4 s0 = *(const float4*)(&scs[c]);
        float4 s1 = *(const float4*)(&scs[c + 4]);
        float4 h0 = *(const float4*)(&shs[c]);
        float4 h4 = *(const float4*)(&shs[c + 4]);
        float4 g0 = *(const float4*)(&lgs[c]);
        float4 g1 = *(const float4*)(&lgs[c + 4]);
        float4 b0 = *(const float4*)(&lbs[c]);
        float4 b1 = *(const float4*)(&lbs[c + 4]);
        float y0 = g0.x * ((s0.x * bflo(u.x) + h0.x) - mu) * rs + b0.x;
        float y1 = g0.y * ((s0.y * bfhi(u.x) + h0.y) - mu) * rs + b0.y;
        float y2 = g0.z * ((s0.z * bflo(u.y) + h0.z) - mu) * rs + b0.z;
        float y3 = g0.w * ((s0.w * bfhi(u.y) + h0.w) - mu) * rs + b0.w;
        float y4 = g1.x * ((s1.x * bflo(u.z) + h4.x) - mu) * rs + b1.x;
        float y5 = g1.y * ((s1.y * bfhi(u.z) + h4.y) - mu) * rs + b1.y;
        float y6 = g1.z * ((s1.z * bflo(u.w) + h4.z) - mu) * rs + b1.z;
        float y7 = g1.w * ((s1.w * bfhi(u.w) + h4.w) - mu) * rs + b1.w;
        av.x = pack2(y0, y1); av.y = pack2(y2, y3);
        av.z = pack2(y4, y5); av.w = pack2(y6, y7);
        *(uint4*)(h1 + (size_t)arow * H_DIM + c) = av;
      }
      *(uint4*)(&As[sr * 40 + sk]) = av;
    }
    #pragma unroll
    for (int j = 0; j < 4; ++j){
      int brow = sr + 64 * j;
      uint4 bv = *(const uint4*)(Bt + (size_t)brow * H_DIM + k0 + sk);
      *(uint4*)(&Bs[brow * 40 + sk]) = bv;
    }
    __syncthreads();
    v8s af[4], bf[4];
    #pragma unroll
    for (int mi = 0; mi < 4; ++mi)
      af[mi] = *(const v8s*)(&As[(mi * 16 + fr) * 40 + quad * 8]);
    #pragma unroll
    for (int ni = 0; ni < 4; ++ni)
      bf[ni] = *(const v8s*)(&Bs[(w * 64 + ni * 16 + fr) * 40 + quad * 8]);
    #pragma unroll
    for (int mi = 0; mi < 4; ++mi)
      #pragma unroll
      for (int ni = 0; ni < 4; ++ni)
        acc[mi][ni] = __builtin_amdgcn_mfma_f32_16x16x32_bf16(af[mi], bf[ni], acc[mi][ni], 0, 0, 0);
  }
  __syncthreads();
  short* Cs = smem; // [64][264]
  #pragma unroll
  for (int mi = 0; mi < 4; ++mi)
    #pragma unroll
    for (int ni = 0; ni < 4; ++ni)
      #pragma unroll
      for (int r = 0; r < 4; ++r){
        int row = mi * 16 + quad * 4 + r;
        int col = w * 64 + ni * 16 + fr;
        Cs[row * 264 + col] = (short)f2bf(acc[mi][ni][r] * dvs[row]);
      }
  __syncthreads();
  int orow = t >> 2;
  int grow = m0 + orow;
  if (grow < M){
    #pragma unroll
    for (int j = 0; j < 4; ++j){
      int oc = (t & 3) * 16 + 64 * j;
      v8s v0 = *(const v8s*)(&Cs[orow * 264 + oc]);
      v8s v1 = *(const v8s*)(&Cs[orow * 264 + oc + 8]);
      *(v8s*)(&C[(size_t)(oc >> 5) * SLICE_ELEMS + (size_t)grow * 32 + (oc & 31)]) = v0;
      int oc1 = oc + 8;
      *(v8s*)(&C[(size_t)(oc1 >> 5) * SLICE_ELEMS + (size_t)grow * 32 + (oc1 & 31)]) = v1;
    }
  }
}

#define ACCP(u, A) { v2f d_ = {bflo(u), bfhi(u)}; A += d_; }
#define ACC8(vv) ACCP(vv.x, A0) ACCP(vv.y, A1) ACCP(vv.z, A2) ACCP(vv.w, A3)

// ---------------- edge aggregation: 4 threads/node, uint4 gathers, 64 nodes/block (256 threads),
//                  LDS edge staging, packed f32 accumulate; BN col-sums folded via atomics ----------------
__global__ __launch_bounds__(256, 4) void agg_k(const unsigned short* hs, const int* offsets,
                                                const unsigned short* edges, const int* perm,
                                                const float* dinv, const float* bias,
                                                unsigned short* g, float* Sg, float* Qg){
  __shared__ unsigned eds32[EDGE_CHUNK / 2];
  __shared__ float wps[4][4][16];
  int t = threadIdx.x;
  int lane = t & 63;
  int wv = t >> 6;
  int slice = blockIdx.x & 7;
  int l4 = lane & 3;
  int grp = blockIdx.x >> 3;
  int nb = grp * 64;
  int idx = nb + (t >> 2);
  int lastn = min(nb + 64, N_NODES);
  int blk0 = offsets[nb];
  int base = blk0 & ~1;
  int blkN = offsets[lastn];
  const unsigned* gsrc = (const unsigned*)(edges + base);
  int nu = min((blkN - base + 1) >> 1, EDGE_CHUNK / 2);
  for (int i = t; i < nu; i += 256)
    eds32[i] = gsrc[i];
  __syncthreads();
  bool act = idx < N_NODES;
  int node = act ? perm[idx] : 0;
  float dvv = act ? dinv[node] : 0.f;
  const uint4* hb4 = (const uint4*)(hs + (size_t)slice * SLICE_ELEMS);
  float4 bb0 = *(const float4*)(bias + slice * 32 + l4 * 8);
  float4 bb1 = *(const float4*)(bias + slice * 32 + l4 * 8 + 4);
  uint4 sv = hb4[(size_t)node * 4 + l4];
  v2f A0 = {bflo(sv.x), bfhi(sv.x)};
  v2f A1 = {bflo(sv.y), bfhi(sv.y)};
  v2f A2 = {bflo(sv.z), bfhi(sv.z)};
  v2f A3 = {bflo(sv.w), bfhi(sv.w)};
  int e  = act ? offsets[idx] : 0;
  int e1 = act ? offsets[idx + 1] : 0;
  if ((e & 1) && e < e1){
    int ru = (e - base) >> 1;
    unsigned d = (ru < EDGE_CHUNK / 2) ? eds32[ru] : gsrc[ru];
    uint4 vv = hb4[(size_t)(d >> 16) * 4 + l4];
    ACC8(vv);
    ++e;
  }
  for (; e + 16 <= e1; e += 16){
    int ru = (e - base) >> 1;
    unsigned dd[8];
    if (ru + 8 <= EDGE_CHUNK / 2){
      #pragma unroll
      for (int j = 0; j < 8; ++j) dd[j] = eds32[ru + j];
    } else {
      #pragma unroll
      for (int j = 0; j < 8; ++j) dd[j] = gsrc[ru + j];
    }
    uint4 v[16];
    #pragma unroll
    for (int j = 0; j < 8; ++j){
      v[2*j]   = hb4[(size_t)(dd[j] & 0xffffu) * 4 + l4];
      v[2*j+1] = hb4[(size_t)(dd[j] >> 16)     * 4 + l4];
    }
    #pragma unroll
    for (int j = 0; j < 16; ++j){ ACC8(v[j]); }
  }
  if (e + 8 <= e1){
    int ru = (e - base) >> 1;
    unsigned dd[4];
    if (ru + 4 <= EDGE_CHUNK / 2){
      #pragma unroll
      for (int j = 0; j < 4; ++j) dd[j] = eds32[ru + j];
    } else {
      #pragma unroll
      for (int j = 0; j < 4; ++j) dd[j] = gsrc[ru + j];
    }
    uint4 v[8];
    #pragma unroll
    for (int j = 0; j < 4; ++j){
      v[2*j]   = hb4[(size_t)(dd[j] & 0xffffu) * 4 + l4];
      v[2*j+1] = hb4[(size_t)(dd[j] >> 16)     * 4 + l4];
    }
    #pragma unroll
    for (int j = 0; j < 8; ++j){ ACC8(v[j]); }
    e += 8;
  }
  if (e + 4 <= e1){
    int ru = (e - base) >> 1;
    unsigned dd0, dd1;
    if (ru + 2 <= EDGE_CHUNK / 2){
      dd0 = eds32[ru]; dd1 = eds32[ru + 1];
    } else {
      dd0 = gsrc[ru]; dd1 = gsrc[ru + 1];
    }
    uint4 v[4];
    v[0] = hb4[(size_t)(dd0 & 0xffffu) * 4 + l4];
    v[1] = hb4[(size_t)(dd0 >> 16)     * 4 + l4];
    v[2] = hb4[(size_t)(dd1 & 0xffffu) * 4 + l4];
    v[3] = hb4[(size_t)(dd1 >> 16)     * 4 + l4];
    #pragma unroll
    for (int j = 0; j < 4; ++j){ ACC8(v[j]); }
    e += 4;
  }
  for (; e < e1; ++e){
    int r = e - base;
    unsigned d = ((r >> 1) < EDGE_CHUNK / 2) ? eds32[r >> 1] : gsrc[r >> 1];
    unsigned s = (r & 1) ? (d >> 16) : (d & 0xffffu);
    uint4 vv = hb4[(size_t)s * 4 + l4];
    ACC8(vv);
  }
  float y0 = act ? fmaxf(dvv * A0.x + bb0.x, 0.f) : 0.f;
  float y1 = act ? fmaxf(dvv * A0.y + bb0.y, 0.f) : 0.f;
  float y2 = act ? fmaxf(dvv * A1.x + bb0.z, 0.f) : 0.f;
  float y3 = act ? fmaxf(dvv * A1.y + bb0.w, 0.f) : 0.f;
  float y4 = act ? fmaxf(dvv * A2.x + bb1.x, 0.f) : 0.f;
  float y5 = act ? fmaxf(dvv * A2.y + bb1.y, 0.f) : 0.f;
  float y6 = act ? fmaxf(dvv * A3.x + bb1.z, 0.f) : 0.f;
  float y7 = act ? fmaxf(dvv * A3.y + bb1.w, 0.f) : 0.f;
  if (act){
    v4u o;
    o.x = pack2(y0, y1); o.y = pack2(y2, y3);
    o.z = pack2(y4, y5); o.w = pack2(y6, y7);
    __builtin_nontemporal_store(o, (v4u*)(g + (size_t)node * H_DIM + slice * 32 + l4 * 8));
  }
  float q0 = y0*y0, q1 = y1*y1, q2 = y2*y2, q3 = y3*y3;
  float q4 = y4*y4, q5 = y5*y5, q6 = y6*y6, q7 = y7*y7;
  #pragma unroll
  for (int m = 4; m < 64; m <<= 1){
    y0 += __shfl_xor(y0, m, 64); y1 += __shfl_xor(y1, m, 64);
    y2 += __shfl_xor(y2, m, 64); y3 += __shfl_xor(y3, m, 64);
    y4 += __shfl_xor(y4, m, 64); y5 += __shfl_xor(y5, m, 64);
    y6 += __shfl_xor(y6, m, 64); y7 += __shfl_xor(y7, m, 64);
    q0 += __shfl_xor(q0, m, 64); q1 += __shfl_xor(q1, m, 64);
    q2 += __shfl_xor(q2, m, 64); q3 += __shfl_xor(q3, m, 64);
    q4 += __shfl_xor(q4, m, 64); q5 += __shfl_xor(q5, m, 64);
    q6 += __shfl_xor(q6, m, 64); q7 += __shfl_xor(q7, m, 64);
  }
  if (lane < 4){
    wps[wv][lane][0] = y0; wps[wv][lane][1] = y1; wps[wv][lane][2] = y2; wps[wv][lane][3] = y3;
    wps[wv][lane][4] = y4; wps[wv][lane][5] = y5; wps[wv][lane][6] = y6; wps[wv][lane][7] = y7;
    wps[wv][lane][8] = q0; wps[wv][lane][9] = q1; wps[wv][lane][10] = q2; wps[wv][lane][11] = q3;
    wps[wv][lane][12] = q4; wps[wv][lane][13] = q5; wps[wv][lane][14] = q6; wps[wv][lane][15] = q7;
  }
  __syncthreads();
  if (t < 64){
    int tl = t >> 4, ti = t & 15;
    float v = wps[0][tl][ti] + wps[1][tl][ti] + wps[2][tl][ti] + wps[3][tl][ti];
    int col32 = tl * 8 + (ti & 7);
    if (ti < 8) atomicAdd(&Sg[slice * 32 + col32], v);
    else        atomicAdd(&Qg[slice * 32 + col32], v);
  }
}

// ---------------- layer 2 apply + residual + output GEMM; BN coeffs derived inline ----------------
__global__ __launch_bounds__(256) void apply2_k(const unsigned short* g,
                                                const float* Sg, const float* Qg,
                                                const float* bng, const float* bnb,
                                                const float* lng, const float* lnb,
                                                const unsigned short* h1, const float* Wout,
                                                const float* bout, float* out){
  int t = threadIdx.x;
  int lane32 = t & 31;
  int row = blockIdx.x * 8 + (t >> 5);
  if (row >= N_NODES) return;
  int c = lane32 * 8;
  const float invN = 1.0f / N_NODES;
  float4 S0 = *(const float4*)(Sg + c), S1 = *(const float4*)(Sg + c + 4);
  float4 Q0 = *(const float4*)(Qg + c), Q1 = *(const float4*)(Qg + c + 4);
  float4 G0 = *(const float4*)(bng + c), G1 = *(const float4*)(bng + c + 4);
  float4 B0 = *(const float4*)(bnb + c), B1 = *(const float4*)(bnb + c + 4);
  float Sa[8] = {S0.x,S0.y,S0.z,S0.w,S1.x,S1.y,S1.z,S1.w};
  float Qa[8] = {Q0.x,Q0.y,Q0.z,Q0.w,Q1.x,Q1.y,Q1.z,Q1.w};
  float Ga[8] = {G0.x,G0.y,G0.z,G0.w,G1.x,G1.y,G1.z,G1.w};
  float Ba[8] = {B0.x,B0.y,B0.z,B0.w,B1.x,B1.y,B1.z,B1.w};
  float scv[8], shv[8];
  #pragma unroll
  for (int j = 0; j < 8; ++j){
    float mu = Sa[j] * invN;
    float rs = rsqrtf(Qa[j] * invN - mu * mu + BN_EPS);
    float s = Ga[j] * rs;
    scv[j] = s; shv[j] = Ba[j] - s * mu;
  }
  uint4 u = *(const uint4*)(g + (size_t)row * H_DIM + c);
  float v0 = scv[0] * bflo(u.x) + shv[0];
  float v1 = scv[1] * bfhi(u.x) + shv[1];
  float v2 = scv[2] * bflo(u.y) + shv[2];
  float v3 = scv[3] * bfhi(u.y) + shv[3];
  float v4 = scv[4] * bflo(u.z) + shv[4];
  float v5 = scv[5] * bfhi(u.z) + shv[5];
  float v6 = scv[6] * bflo(u.w) + shv[6];
  float v7 = scv[7] * bfhi(u.w) + shv[7];
  float sum = v0+v1+v2+v3+v4+v5+v6+v7;
  float sq  = v0*v0+v1*v1+v2*v2+v3*v3+v4*v4+v5*v5+v6*v6+v7*v7;
  #pragma unroll
  for (int m = 1; m < 32; m <<= 1){ sum += __shfl_xor(sum, m, 64); sq += __shfl_xor(sq, m, 64); }
  float mu = sum * (1.0f / H_DIM);
  float var = sq * (1.0f / H_DIM) - mu * mu;
  float rs = rsqrtf(var + LN_EPS);
  float4 g40 = *(const float4*)(lng + c);
  float4 g41 = *(const float4*)(lng + c + 4);
  float4 b40 = *(const float4*)(lnb + c);
  float4 b41 = *(const float4*)(lnb + c + 4);
  uint4 hr = *(const uint4*)(h1 + (size_t)row * H_DIM + c);
  float y0 = g40.x * (v0 - mu) * rs + b40.x + bflo(hr.x);
  float y1 = g40.y * (v1 - mu) * rs + b40.y + bfhi(hr.x);
  float y2 = g40.z * (v2 - mu) * rs + b40.z + bflo(hr.y);
  float y3 = g40.w * (v3 - mu) * rs + b40.w + bfhi(hr.y);
  float y4 = g41.x * (v4 - mu) * rs + b41.x + bflo(hr.z);
  float y5 = g41.y * (v5 - mu) * rs + b41.y + bfhi(hr.z);
  float y6 = g41.z * (v6 - mu) * rs + b41.z + bflo(hr.w);
  float y7 = g41.w * (v7 - mu) * rs + b41.w + bfhi(hr.w);
  float4 w0 = *(const float4*)(Wout + c * 2);
  float4 w1 = *(const float4*)(Wout + c * 2 + 4);
  float4 w2 = *(const float4*)(Wout + c * 2 + 8);
  float4 w3 = *(const float4*)(Wout + c * 2 + 12);
  float o0 = y0*w0.x + y1*w0.z + y2*w1.x + y3*w1.z + y4*w2.x + y5*w2.z + y6*w3.x + y7*w3.z;
  float o1 = y0*w0.y + y1*w0.w + y2*w1.y + y3*w1.w + y4*w2.y + y5*w2.w + y6*w3.y + y7*w3.w;
  #pragma unroll
  for (int m = 1; m < 32; m <<= 1){ o0 += __shfl_xor(o0, m, 64); o1 += __shfl_xor(o1, m, 64); }
  if (lane32 == 0){
    out[(size_t)row * 2 + 0] = o0 + bout[0];
    out[(size_t)row * 2 + 1] = o1 + bout[1];
  }
}

extern "C" void kernel_launch(void* const* d_in, const int* in_sizes, int n_in,
                              void* d_out, int out_size, void* d_ws, size_t ws_size,
                              hipStream_t stream) {
  const float* x    = (const float*)d_in[0];
  const int*   ei   = (const int*)d_in[1];
  const float* fs   = (const float*)d_in[2];
  const float* fb   = (const float*)d_in[3];
  const float* bn0g = (const float*)d_in[4];
  const float* bn0b = (const float*)d_in[5];
  const float* W1   = (const float*)d_in[6];
  const float* b1   = (const float*)d_in[7];
  const float* bn1g = (const float*)d_in[8];
  const float* bn1b = (const float*)d_in[9];
  const float* ln1g = (const float*)d_in[10];
  const float* ln1b = (const float*)d_in[11];
  const float* W2   = (const float*)d_in[12];
  const float* b2   = (const float*)d_in[13];
  const float* bn2g = (const float*)d_in[14];
  const float* bn2b = (const float*)d_in[15];
  const float* ln2g = (const float*)d_in[16];
  const float* ln2b = (const float*)d_in[17];
  const float* Wout = (const float*)d_in[18];
  const float* bout = (const float*)d_in[19];
  float* out = (float*)d_out;

  char* w = (char*)d_ws;
  float* bn0S  = (float*)(w + 0);          // [8][128] -> 4096
  float* bn0Q  = (float*)(w + 4096);       // -> 8192
  int*   ghist  = (int*)(w + 8192);        // 196 ints -> 8976
  int*   gcursor= (int*)(w + 8976);        // 196 ints -> 9760
  float* Sg1   = (float*)(w + 9760);       // 1024 -> 10784
  float* Qg1   = (float*)(w + 10784);      // -> 11808
  float* Sg2   = (float*)(w + 11808);      // -> 12832
  float* Qg2   = (float*)(w + 12832);      // -> 13856
  const size_t ZERO_BYTES = 13856;
  float* dinv  = (float*)(w + 211584);     // 200000 -> 411584
  int*   offs  = (int*)(w + 411584);       // 200004 -> pad 611712
  int*   perm  = (int*)(w + 611712);       // 200000 -> 811712
  unsigned short* edges = (unsigned short*)(w + 1011712); // 1600000 -> 2611712
  unsigned short* W1t  = (unsigned short*)(w + 15411712);  // -> 15477248
  unsigned short* W2t  = (unsigned short*)(w + 15477248);  // -> 15608320
  unsigned short* hlin = (unsigned short*)(w + 15608320);  // 25.6 MB -> 41208320
  unsigned*       ebuf = (unsigned*)(w + 15608320);        // aliases hlin (3.2 MB, dead before gemm1)
  unsigned short* gbuf = (unsigned short*)(w + 41208320);  // 25.6 MB -> 66808320
  unsigned short* h1   = (unsigned short*)(w + 66808320);  // 25.6 MB -> 92408320

  (void)in_sizes; (void)n_in; (void)out_size; (void)ws_size;

  hipMemsetAsync(d_ws, 0, ZERO_BYTES, stream);

  // preprocessing: bucketed counting sort, fused per-bucket degree-sort+scatter
  bn0r1_k<<<BN0_BLOCKS + RCHUNKS, 256, 0, stream>>>(ei, x, fs, fb, bn0S, bn0Q, ghist);
  r3_k<<<RCHUNKS, 256, 0, stream>>>(ei, ghist, gcursor, ebuf);
  sortprep_k<<<NBKT + TR_BLOCKS, 256, 0, stream>>>(
      ebuf, ghist, perm, offs, dinv, edges, W1, W2, W1t, W2t);

  int g1grid = (N_NODES + 127) / 128;
  int g2grid = (N_NODES + 63) / 64;
  int agg_blocks = NBLK2 * 8;

  // ---- layer 1 (BN0 apply fused into gemm1 A-staging; BN1 col-sums folded into agg atomics) ----
  gemm1_k<<<g1grid, 512, 0, stream>>>(x, bn0S, bn0Q, fs, fb, bn0g, bn0b, W1t, dinv, hlin, N_NODES);
  agg_k<<<agg_blocks, 256, 0, stream>>>(hlin, offs, edges, perm, dinv, b1, gbuf, Sg1, Qg1);

  // ---- layer 2 (BN1+LN1 fused into gemm2 A-staging, gemm_k tile structure; h1 byproduct) ----
  gemm2_k<<<g2grid, 256, 0, stream>>>(gbuf, Sg1, Qg1, bn1g, bn1b, ln1g, ln1b, W2t, dinv, hlin, h1, N_NODES);
  agg_k<<<agg_blocks, 256, 0, stream>>>(hlin, offs, edges, perm, dinv, b2, gbuf, Sg2, Qg2);
  apply2_k<<<(N_NODES + 7) / 8, 256, 0, stream>>>(gbuf, Sg2, Qg2, bn2g, bn2b, ln2g, ln2b, h1, Wout, bout, out);
}